// Round 10
// baseline (425.857 us; speedup 1.0000x reference)
//
#include <hip/hip_runtime.h>
#include <hip/hip_bf16.h>
#include <hip/hip_fp16.h>
#include <math.h>

#define N_NODES 100000
#define N_EDGES 1600000
#define F_IN 16
#define HDIM 64
#define E_DIM 9
#define NEG 0.2f

#define CAP 64                            // bucket capacity/node (Poisson(16), 12-sigma)
#define NSLICE 8
#define SLICE_W 12500                     // dst-slice width (100000/8)
#define SLICE_CAP 210000                  // per-slice stream capacity (binomial +24 sigma)
#define PART_BLOCKS 1024                  // 8 slices x 128 blocks
#define FIXSCALE 16777216.0f              // 2^24 fixed-point for sum_ae

typedef unsigned long long ull;
typedef long long ll;

// ---- K1: h = x@W (wave per node) -> bf16; a_src/a_dst computed in fp32 ----
__global__ __launch_bounds__(256) void k_node_h(
    const float* __restrict__ x, const float* __restrict__ W,
    const float* __restrict__ att_src, const float* __restrict__ att_dst,
    __hip_bfloat16* __restrict__ hbf, float* __restrict__ a_src,
    float* __restrict__ a_dst) {
  __shared__ float sW[F_IN * HDIM];
  int t = threadIdx.x;
  for (int i = t; i < F_IN * HDIM; i += 256) sW[i] = W[i];
  __syncthreads();
  int lane = t & 63;
  int node = blockIdx.x * 4 + (t >> 6);
  if (node >= N_NODES) return;
  const float* xr = x + node * F_IN;
  float acc = 0.f;
#pragma unroll
  for (int k = 0; k < F_IN; ++k) acc += xr[k] * sW[k * HDIM + lane];
  hbf[(size_t)node * HDIM + lane] = __float2bfloat16(acc);
  float v1 = acc * att_src[lane];
  float v2 = acc * att_dst[lane];
#pragma unroll
  for (int off = 32; off > 0; off >>= 1) {
    v1 += __shfl_down(v1, off);
    v2 += __shfl_down(v2, off);
  }
  if (lane == 0) { a_src[node] = v1; a_dst[node] = v2; }
}

// ---- tiny: w_e[d] = sum_h W_edge[d,h]*att_edge[h] ----
__global__ void k_we(const float* __restrict__ W_edge,
                     const float* __restrict__ att_edge, float* __restrict__ w_e) {
  int d = threadIdx.x;
  if (d < E_DIM) {
    float s = 0.f;
    for (int hh = 0; hh < HDIM; ++hh) s += W_edge[d * HDIM + hh] * att_edge[hh];
    w_e[d] = s;
  }
}

// ---- K2: per-edge math + 8-way dst-slice partition, BALLOT compaction.
// Per wave, per slice: __ballot -> rank/count (pure VALU, no LDS atomics).
// 8 global reservation atomics per block (50K total). Lanes store entries
// directly to per-slice streams (8 contiguous runs per wave).
// Entry = {dst_local:14 | fp16(a_e):16 | pk:32}. N_EDGES = 6250*256 exact. ----
__global__ __launch_bounds__(256) void k_edge_pre(
    const float* __restrict__ ea, const int* __restrict__ ei,
    const float* __restrict__ w_e, const float* __restrict__ a_src,
    const float* __restrict__ a_dst, ull* __restrict__ sstream,
    unsigned* __restrict__ gcount) {
  __shared__ float swe[E_DIM];
  __shared__ unsigned wcnt[4][NSLICE];   // per-wave per-slice counts
  __shared__ unsigned woff[4][NSLICE];   // per-wave exclusive prefix (block-local)
  __shared__ unsigned gbase[NSLICE];     // global reservation base
  int t = threadIdx.x;
  int wave = t >> 6, lane = t & 63;
  if (t < E_DIM) swe[t] = w_e[t];
  __syncthreads();
  int e = blockIdx.x * 256 + t;
  int s = __builtin_nontemporal_load(ei + e);
  int d = __builtin_nontemporal_load(ei + N_EDGES + e);
  float a_e = 0.f;
#pragma unroll
  for (int k = 0; k < E_DIM; ++k)
    a_e += __builtin_nontemporal_load(ea + (size_t)e * E_DIM + k) * swe[k];
  float al = a_src[s] + a_dst[d] + a_e;
  al = al >= 0.f ? al : NEG * al;
  float ee = expf(al);  // shift-invariant softmax: max-subtract skipped
  // round-to-nearest-even bf16; ee>0 so sign bit free -> 15 bits
  unsigned b = __float_as_uint(ee);
  b += 0x7fffu + ((b >> 16) & 1u);
  unsigned pk = ((unsigned)s << 15) | ((b >> 16) & 0x7fffu);
  unsigned slice = (unsigned)d / SLICE_W;
  unsigned dloc = (unsigned)d - slice * SLICE_W;
  unsigned aeh = (unsigned)__half_as_ushort(__float2half(a_e));
  ull entry = ((ull)dloc << 48) | ((ull)aeh << 32) | (ull)pk;
  // wave-level ranking via ballot (all lanes execute all 8 ballots)
  ull lt = (lane == 63) ? 0x7FFFFFFFFFFFFFFFull : ((1ull << lane) - 1ull);
  unsigned myrank = 0;
#pragma unroll
  for (int si = 0; si < NSLICE; ++si) {
    ull m = __ballot(slice == (unsigned)si);
    if (slice == (unsigned)si) myrank = (unsigned)__popcll(m & lt);
    if (lane == 0) wcnt[wave][si] = (unsigned)__popcll(m);
  }
  __syncthreads();
  if (t < NSLICE) {  // thread t handles slice t: per-wave prefix + reservation
    unsigned a = 0;
#pragma unroll
    for (int w = 0; w < 4; ++w) { woff[w][t] = a; a += wcnt[w][t]; }
    gbase[t] = atomicAdd(gcount + t, a);
  }
  __syncthreads();
  unsigned off = gbase[slice] + woff[wave][slice] + myrank;
  if (off < SLICE_CAP)
    __builtin_nontemporal_store(entry, sstream + (size_t)slice * SLICE_CAP + off);
}

// ---- K3: distribute within slice. Each slice's entries are contiguous;
// every byte read once, coalesced. One fused 64-bit atomic per edge:
// count++ (low 20b, old value = bucket pos) + sum_ae in 2^-24 fixpt (high 44b).
// blockIdx%8 round-robin -> slice buckets (3.2 MB) stay in one XCD's L2. ----
__global__ __launch_bounds__(256) void k_part2(
    const ull* __restrict__ sstream, const unsigned* __restrict__ gcount,
    ull* __restrict__ packed, unsigned* __restrict__ bpack) {
  int t = threadIdx.x;
  int slice = blockIdx.x & (NSLICE - 1);
  int j = blockIdx.x >> 3;
  unsigned n = gcount[slice];
  const ull* sp = sstream + (size_t)slice * SLICE_CAP;
  int lo = slice * SLICE_W;
  const unsigned stride = (PART_BLOCKS / NSLICE) * 256;
  for (unsigned i = (unsigned)j * 256 + t; i < n; i += stride) {
    ull entry = sp[i];
    int d = lo + (int)(unsigned)(entry >> 48);
    float ae = __half2float(__ushort_as_half((unsigned short)((entry >> 32) & 0xFFFFu)));
    unsigned pk = (unsigned)(entry & 0xFFFFFFFFu);
    ll q = (ll)lrintf(ae * FIXSCALE);
    ull old = atomicAdd(packed + d, ((ull)q << 20) | 1ull);
    unsigned pos = (unsigned)(old & 0xFFFFFu);
    if (pos < CAP) bpack[(size_t)d * CAP + pos] = pk;
  }
}

// ---- K4: gather: decode packed (deg+sum_ae), denom + weighted bf16-h
// aggregate from fixed-stride bucket (aligned uint4 loads, 8-way unroll),
// self-loop, relu/bias/lin_w dot (wave per node). ----
__global__ __launch_bounds__(256) void k_gather(
    const ull* __restrict__ packed, const unsigned* __restrict__ bpack,
    const __hip_bfloat16* __restrict__ hbf, const float* __restrict__ a_src,
    const float* __restrict__ a_dst, const float* __restrict__ bias,
    const float* __restrict__ lin_w, float* __restrict__ s_node) {
  int t = threadIdx.x;
  int lane = t & 63;
  int node = blockIdx.x * 4 + (t >> 6);
  if (node >= N_NODES) return;
  ull p = packed[node];
  unsigned deg = (unsigned)(p & 0xFFFFFu);
  float sumae = (float)((double)((ll)p >> 20) * (1.0 / (double)FIXSCALE));
  const unsigned* row = bpack + (size_t)node * CAP;
  float acc = 0.f, denom = 0.f;
  unsigned k = 0;
  for (; k + 8 <= deg; k += 8) {
    uint4 pa = *(const uint4*)(row + k);
    uint4 pb = *(const uint4*)(row + k + 4);
    float e0 = __uint_as_float((pa.x & 0x7fffu) << 16);
    float e1 = __uint_as_float((pa.y & 0x7fffu) << 16);
    float e2 = __uint_as_float((pa.z & 0x7fffu) << 16);
    float e3 = __uint_as_float((pa.w & 0x7fffu) << 16);
    float e4 = __uint_as_float((pb.x & 0x7fffu) << 16);
    float e5 = __uint_as_float((pb.y & 0x7fffu) << 16);
    float e6 = __uint_as_float((pb.z & 0x7fffu) << 16);
    float e7 = __uint_as_float((pb.w & 0x7fffu) << 16);
    float h0 = __bfloat162float(hbf[(size_t)(pa.x >> 15) * HDIM + lane]);
    float h1 = __bfloat162float(hbf[(size_t)(pa.y >> 15) * HDIM + lane]);
    float h2 = __bfloat162float(hbf[(size_t)(pa.z >> 15) * HDIM + lane]);
    float h3 = __bfloat162float(hbf[(size_t)(pa.w >> 15) * HDIM + lane]);
    float h4 = __bfloat162float(hbf[(size_t)(pb.x >> 15) * HDIM + lane]);
    float h5 = __bfloat162float(hbf[(size_t)(pb.y >> 15) * HDIM + lane]);
    float h6 = __bfloat162float(hbf[(size_t)(pb.z >> 15) * HDIM + lane]);
    float h7 = __bfloat162float(hbf[(size_t)(pb.w >> 15) * HDIM + lane]);
    denom += ((e0 + e1) + (e2 + e3)) + ((e4 + e5) + (e6 + e7));
    acc += (e0 * h0 + e1 * h1 + e2 * h2 + e3 * h3)
         + (e4 * h4 + e5 * h5 + e6 * h6 + e7 * h7);
  }
  for (; k + 4 <= deg; k += 4) {
    uint4 p4 = *(const uint4*)(row + k);
    float e0 = __uint_as_float((p4.x & 0x7fffu) << 16);
    float e1 = __uint_as_float((p4.y & 0x7fffu) << 16);
    float e2 = __uint_as_float((p4.z & 0x7fffu) << 16);
    float e3 = __uint_as_float((p4.w & 0x7fffu) << 16);
    float h0 = __bfloat162float(hbf[(size_t)(p4.x >> 15) * HDIM + lane]);
    float h1 = __bfloat162float(hbf[(size_t)(p4.y >> 15) * HDIM + lane]);
    float h2 = __bfloat162float(hbf[(size_t)(p4.z >> 15) * HDIM + lane]);
    float h3 = __bfloat162float(hbf[(size_t)(p4.w >> 15) * HDIM + lane]);
    denom += (e0 + e1) + (e2 + e3);
    acc += e0 * h0 + e1 * h1 + e2 * h2 + e3 * h3;
  }
  for (; k < deg; ++k) {
    unsigned pe = row[k];
    float ee = __uint_as_float((pe & 0x7fffu) << 16);
    denom += ee;
    acc += ee * __bfloat162float(hbf[(size_t)(pe >> 15) * HDIM + lane]);
  }
  // self-loop (fill_value='mean'): logit uses mean of incident a_e
  float cnt = (float)deg;
  float all = a_src[node] + a_dst[node] + sumae / fmaxf(cnt, 1.f);
  all = all >= 0.f ? all : NEG * all;
  float eel = expf(all);
  denom += eel;
  acc += eel * __bfloat162float(hbf[(size_t)node * HDIM + lane]);
  float o = fmaxf(acc / (denom + 1e-16f) + bias[lane], 0.f) * lin_w[lane];
#pragma unroll
  for (int off = 32; off > 0; off >>= 1) o += __shfl_down(o, off);
  if (lane == 0) s_node[node] = o;
}

// ---- K5: out[e] = sigmoid(0.5*(s[src]+s[dst]) + lin_b) ----
__global__ __launch_bounds__(256) void k_out(
    const int* __restrict__ ei, const float* __restrict__ s_node,
    const float* __restrict__ lin_b, float* __restrict__ out) {
  int e = blockIdx.x * 256 + threadIdx.x;
  if (e >= N_EDGES) return;
  int s = __builtin_nontemporal_load(ei + e);
  int d = __builtin_nontemporal_load(ei + N_EDGES + e);
  float z = 0.5f * (s_node[s] + s_node[d]) + lin_b[0];
  float r = 1.f / (1.f + expf(-z));
  __builtin_nontemporal_store(r, out + e);
}

extern "C" void kernel_launch(void* const* d_in, const int* in_sizes, int n_in,
                              void* d_out, int out_size, void* d_ws, size_t ws_size,
                              hipStream_t stream) {
  const float* x        = (const float*)d_in[0];
  const float* edge_attr= (const float*)d_in[1];
  const float* W        = (const float*)d_in[2];
  const float* W_edge   = (const float*)d_in[3];
  const float* att_src  = (const float*)d_in[4];
  const float* att_dst  = (const float*)d_in[5];
  const float* att_edge = (const float*)d_in[6];
  const float* bias     = (const float*)d_in[7];
  const float* lin_w    = (const float*)d_in[8];
  const float* lin_b    = (const float*)d_in[9];
  const int*   ei       = (const int*)d_in[10];
  float* out = (float*)d_out;

  // workspace layout (8-B alignment preserved: every region size mult of 8 B)
  char* base = (char*)d_ws;
  __hip_bfloat16* hbf = (__hip_bfloat16*)base;                      // 12.8 MB
  ull* sstream = (ull*)(base + (size_t)N_NODES * HDIM * 2);         // 8*210000*8 = 13.44 MB
  unsigned* bpack = (unsigned*)(sstream + (size_t)NSLICE * SLICE_CAP); // N*CAP*4 = 25.6 MB
  ull* packed = (ull*)(bpack + (size_t)N_NODES * CAP);              // N*8 = 0.8 MB (zeroed)
  unsigned* gcount = (unsigned*)(packed + N_NODES);                 // 8 u32 (zeroed)
  float* a_src  = (float*)(gcount + NSLICE);                        // N
  float* a_dst  = a_src + N_NODES;                                  // N
  float* s_node = a_dst + N_NODES;                                  // N
  float* w_e    = s_node + N_NODES;                                 // 16
  // total ~ 53.9 MB

  hipMemsetAsync(packed, 0, sizeof(ull) * N_NODES + sizeof(unsigned) * NSLICE, stream);

  int nb_node   = (N_NODES + 3) / 4;
  int nb_edge_t = N_EDGES / 256;   // 6250, exact

  k_node_h  <<<nb_node, 256, 0, stream>>>(x, W, att_src, att_dst, hbf, a_src, a_dst);
  k_we      <<<1, 64, 0, stream>>>(W_edge, att_edge, w_e);
  k_edge_pre<<<nb_edge_t, 256, 0, stream>>>(edge_attr, ei, w_e, a_src, a_dst,
                                            sstream, gcount);
  k_part2   <<<PART_BLOCKS, 256, 0, stream>>>(sstream, gcount, packed, bpack);
  k_gather  <<<nb_node, 256, 0, stream>>>(packed, bpack, hbf, a_src, a_dst,
                                          bias, lin_w, s_node);
  k_out     <<<nb_edge_t, 256, 0, stream>>>(ei, s_node, lin_b, out);
}

// Round 11
// 419.876 us; speedup vs baseline: 1.0142x; 1.0142x over previous
//
#include <hip/hip_runtime.h>
#include <hip/hip_bf16.h>
#include <hip/hip_fp16.h>
#include <math.h>

#define N_NODES 100000
#define N_EDGES 1600000
#define F_IN 16
#define HDIM 64
#define E_DIM 9
#define NEG 0.2f

#define CAP 64                            // bucket capacity/node (Poisson(16), 12-sigma)
#define NSLICE 8
#define SLICE_W 12500                     // dst-slice width (100000/8)
#define SLICE_CAP 210000                  // per-slice stream capacity (binomial +24 sigma)
#define PART_BLOCKS 1024                  // 8 slices x 128 blocks
#define FIXSCALE 16777216.0f              // 2^24 fixed-point for sum_ae

typedef unsigned long long ull;
typedef long long ll;

// ---- K1: h = x@W (wave per node) -> bf16; a_src/a_dst computed in fp32 ----
__global__ __launch_bounds__(256) void k_node_h(
    const float* __restrict__ x, const float* __restrict__ W,
    const float* __restrict__ att_src, const float* __restrict__ att_dst,
    __hip_bfloat16* __restrict__ hbf, float* __restrict__ a_src,
    float* __restrict__ a_dst) {
  __shared__ float sW[F_IN * HDIM];
  int t = threadIdx.x;
  for (int i = t; i < F_IN * HDIM; i += 256) sW[i] = W[i];
  __syncthreads();
  int lane = t & 63;
  int node = blockIdx.x * 4 + (t >> 6);
  if (node >= N_NODES) return;
  const float* xr = x + node * F_IN;
  float acc = 0.f;
#pragma unroll
  for (int k = 0; k < F_IN; ++k) acc += xr[k] * sW[k * HDIM + lane];
  hbf[(size_t)node * HDIM + lane] = __float2bfloat16(acc);
  float v1 = acc * att_src[lane];
  float v2 = acc * att_dst[lane];
#pragma unroll
  for (int off = 32; off > 0; off >>= 1) {
    v1 += __shfl_down(v1, off);
    v2 += __shfl_down(v2, off);
  }
  if (lane == 0) { a_src[node] = v1; a_dst[node] = v2; }
}

// ---- tiny: w_e[d] = sum_h W_edge[d,h]*att_edge[h] ----
__global__ void k_we(const float* __restrict__ W_edge,
                     const float* __restrict__ att_edge, float* __restrict__ w_e) {
  int d = threadIdx.x;
  if (d < E_DIM) {
    float s = 0.f;
    for (int hh = 0; hh < HDIM; ++hh) s += W_edge[d * HDIM + hh] * att_edge[hh];
    w_e[d] = s;
  }
}

// ---- K2: per-edge math + 8-way dst-slice partition, ballot compaction.
// edge_attr tile is LDS-STAGED with coalesced loads (9 loads of stride 256),
// then consumed at sea[t*9+k] (2 lanes/bank = conflict-free). This cuts the
// wave's edge_attr L2 transactions ~324 -> 36 (the R9 limiter).
// Entry = {dst_local:14 | fp16(a_e):16 | pk:32}. N_EDGES = 6250*256 exact. ----
__global__ __launch_bounds__(256) void k_edge_pre(
    const float* __restrict__ ea, const int* __restrict__ ei,
    const float* __restrict__ w_e, const float* __restrict__ a_src,
    const float* __restrict__ a_dst, ull* __restrict__ sstream,
    unsigned* __restrict__ gcount) {
  __shared__ float sea[256 * E_DIM];     // 9216 B staged edge_attr tile
  __shared__ float swe[E_DIM];
  __shared__ unsigned wcnt[4][NSLICE];   // per-wave per-slice counts
  __shared__ unsigned woff[4][NSLICE];   // per-wave exclusive prefix (block-local)
  __shared__ unsigned gbase[NSLICE];     // global reservation base
  int t = threadIdx.x;
  int wave = t >> 6, lane = t & 63;
  if (t < E_DIM) swe[t] = w_e[t];
  // coalesced stage: block's 256x9 floats, each byte read exactly once
  size_t tile = (size_t)blockIdx.x * (256 * E_DIM);
#pragma unroll
  for (int i = 0; i < E_DIM; ++i)
    sea[i * 256 + t] = __builtin_nontemporal_load(ea + tile + i * 256 + t);
  int e = blockIdx.x * 256 + t;
  int s = __builtin_nontemporal_load(ei + e);
  int d = __builtin_nontemporal_load(ei + N_EDGES + e);
  __syncthreads();
  float a_e = 0.f;
#pragma unroll
  for (int k = 0; k < E_DIM; ++k) a_e += sea[t * E_DIM + k] * swe[k];
  float al = a_src[s] + a_dst[d] + a_e;
  al = al >= 0.f ? al : NEG * al;
  float ee = expf(al);  // shift-invariant softmax: max-subtract skipped
  // round-to-nearest-even bf16; ee>0 so sign bit free -> 15 bits
  unsigned b = __float_as_uint(ee);
  b += 0x7fffu + ((b >> 16) & 1u);
  unsigned pk = ((unsigned)s << 15) | ((b >> 16) & 0x7fffu);
  unsigned slice = (unsigned)d / SLICE_W;
  unsigned dloc = (unsigned)d - slice * SLICE_W;
  unsigned aeh = (unsigned)__half_as_ushort(__float2half(a_e));
  ull entry = ((ull)dloc << 48) | ((ull)aeh << 32) | (ull)pk;
  // wave-level ranking via ballot (all lanes execute all 8 ballots)
  ull lt = (lane == 63) ? 0x7FFFFFFFFFFFFFFFull : ((1ull << lane) - 1ull);
  unsigned myrank = 0;
#pragma unroll
  for (int si = 0; si < NSLICE; ++si) {
    ull m = __ballot(slice == (unsigned)si);
    if (slice == (unsigned)si) myrank = (unsigned)__popcll(m & lt);
    if (lane == 0) wcnt[wave][si] = (unsigned)__popcll(m);
  }
  __syncthreads();
  if (t < NSLICE) {  // thread t handles slice t: per-wave prefix + reservation
    unsigned a = 0;
#pragma unroll
    for (int w = 0; w < 4; ++w) { woff[w][t] = a; a += wcnt[w][t]; }
    gbase[t] = atomicAdd(gcount + t, a);
  }
  __syncthreads();
  unsigned off = gbase[slice] + woff[wave][slice] + myrank;
  if (off < SLICE_CAP)
    __builtin_nontemporal_store(entry, sstream + (size_t)slice * SLICE_CAP + off);
}

// ---- K3: distribute within slice. Each slice's entries are contiguous;
// every byte read once, coalesced. One fused 64-bit atomic per edge:
// count++ (low 20b, old value = bucket pos) + sum_ae in 2^-24 fixpt (high 44b).
// blockIdx%8 round-robin -> slice buckets (3.2 MB) stay in one XCD's L2. ----
__global__ __launch_bounds__(256) void k_part2(
    const ull* __restrict__ sstream, const unsigned* __restrict__ gcount,
    ull* __restrict__ packed, unsigned* __restrict__ bpack) {
  int t = threadIdx.x;
  int slice = blockIdx.x & (NSLICE - 1);
  int j = blockIdx.x >> 3;
  unsigned n = gcount[slice];
  const ull* sp = sstream + (size_t)slice * SLICE_CAP;
  int lo = slice * SLICE_W;
  const unsigned stride = (PART_BLOCKS / NSLICE) * 256;
  for (unsigned i = (unsigned)j * 256 + t; i < n; i += stride) {
    ull entry = sp[i];
    int d = lo + (int)(unsigned)(entry >> 48);
    float ae = __half2float(__ushort_as_half((unsigned short)((entry >> 32) & 0xFFFFu)));
    unsigned pk = (unsigned)(entry & 0xFFFFFFFFu);
    ll q = (ll)lrintf(ae * FIXSCALE);
    ull old = atomicAdd(packed + d, ((ull)q << 20) | 1ull);
    unsigned pos = (unsigned)(old & 0xFFFFFu);
    if (pos < CAP) bpack[(size_t)d * CAP + pos] = pk;
  }
}

// ---- K4: gather: decode packed (deg+sum_ae), denom + weighted bf16-h
// aggregate from fixed-stride bucket (aligned uint4 loads, 8-way unroll),
// self-loop, relu/bias/lin_w dot (wave per node). ----
__global__ __launch_bounds__(256) void k_gather(
    const ull* __restrict__ packed, const unsigned* __restrict__ bpack,
    const __hip_bfloat16* __restrict__ hbf, const float* __restrict__ a_src,
    const float* __restrict__ a_dst, const float* __restrict__ bias,
    const float* __restrict__ lin_w, float* __restrict__ s_node) {
  int t = threadIdx.x;
  int lane = t & 63;
  int node = blockIdx.x * 4 + (t >> 6);
  if (node >= N_NODES) return;
  ull p = packed[node];
  unsigned deg = (unsigned)(p & 0xFFFFFu);
  float sumae = (float)((double)((ll)p >> 20) * (1.0 / (double)FIXSCALE));
  const unsigned* row = bpack + (size_t)node * CAP;
  float acc = 0.f, denom = 0.f;
  unsigned k = 0;
  for (; k + 8 <= deg; k += 8) {
    uint4 pa = *(const uint4*)(row + k);
    uint4 pb = *(const uint4*)(row + k + 4);
    float e0 = __uint_as_float((pa.x & 0x7fffu) << 16);
    float e1 = __uint_as_float((pa.y & 0x7fffu) << 16);
    float e2 = __uint_as_float((pa.z & 0x7fffu) << 16);
    float e3 = __uint_as_float((pa.w & 0x7fffu) << 16);
    float e4 = __uint_as_float((pb.x & 0x7fffu) << 16);
    float e5 = __uint_as_float((pb.y & 0x7fffu) << 16);
    float e6 = __uint_as_float((pb.z & 0x7fffu) << 16);
    float e7 = __uint_as_float((pb.w & 0x7fffu) << 16);
    float h0 = __bfloat162float(hbf[(size_t)(pa.x >> 15) * HDIM + lane]);
    float h1 = __bfloat162float(hbf[(size_t)(pa.y >> 15) * HDIM + lane]);
    float h2 = __bfloat162float(hbf[(size_t)(pa.z >> 15) * HDIM + lane]);
    float h3 = __bfloat162float(hbf[(size_t)(pa.w >> 15) * HDIM + lane]);
    float h4 = __bfloat162float(hbf[(size_t)(pb.x >> 15) * HDIM + lane]);
    float h5 = __bfloat162float(hbf[(size_t)(pb.y >> 15) * HDIM + lane]);
    float h6 = __bfloat162float(hbf[(size_t)(pb.z >> 15) * HDIM + lane]);
    float h7 = __bfloat162float(hbf[(size_t)(pb.w >> 15) * HDIM + lane]);
    denom += ((e0 + e1) + (e2 + e3)) + ((e4 + e5) + (e6 + e7));
    acc += (e0 * h0 + e1 * h1 + e2 * h2 + e3 * h3)
         + (e4 * h4 + e5 * h5 + e6 * h6 + e7 * h7);
  }
  for (; k + 4 <= deg; k += 4) {
    uint4 p4 = *(const uint4*)(row + k);
    float e0 = __uint_as_float((p4.x & 0x7fffu) << 16);
    float e1 = __uint_as_float((p4.y & 0x7fffu) << 16);
    float e2 = __uint_as_float((p4.z & 0x7fffu) << 16);
    float e3 = __uint_as_float((p4.w & 0x7fffu) << 16);
    float h0 = __bfloat162float(hbf[(size_t)(p4.x >> 15) * HDIM + lane]);
    float h1 = __bfloat162float(hbf[(size_t)(p4.y >> 15) * HDIM + lane]);
    float h2 = __bfloat162float(hbf[(size_t)(p4.z >> 15) * HDIM + lane]);
    float h3 = __bfloat162float(hbf[(size_t)(p4.w >> 15) * HDIM + lane]);
    denom += (e0 + e1) + (e2 + e3);
    acc += e0 * h0 + e1 * h1 + e2 * h2 + e3 * h3;
  }
  for (; k < deg; ++k) {
    unsigned pe = row[k];
    float ee = __uint_as_float((pe & 0x7fffu) << 16);
    denom += ee;
    acc += ee * __bfloat162float(hbf[(size_t)(pe >> 15) * HDIM + lane]);
  }
  // self-loop (fill_value='mean'): logit uses mean of incident a_e
  float cnt = (float)deg;
  float all = a_src[node] + a_dst[node] + sumae / fmaxf(cnt, 1.f);
  all = all >= 0.f ? all : NEG * all;
  float eel = expf(all);
  denom += eel;
  acc += eel * __bfloat162float(hbf[(size_t)node * HDIM + lane]);
  float o = fmaxf(acc / (denom + 1e-16f) + bias[lane], 0.f) * lin_w[lane];
#pragma unroll
  for (int off = 32; off > 0; off >>= 1) o += __shfl_down(o, off);
  if (lane == 0) s_node[node] = o;
}

// ---- K5: out[e] = sigmoid(0.5*(s[src]+s[dst]) + lin_b) ----
__global__ __launch_bounds__(256) void k_out(
    const int* __restrict__ ei, const float* __restrict__ s_node,
    const float* __restrict__ lin_b, float* __restrict__ out) {
  int e = blockIdx.x * 256 + threadIdx.x;
  if (e >= N_EDGES) return;
  int s = __builtin_nontemporal_load(ei + e);
  int d = __builtin_nontemporal_load(ei + N_EDGES + e);
  float z = 0.5f * (s_node[s] + s_node[d]) + lin_b[0];
  float r = 1.f / (1.f + expf(-z));
  __builtin_nontemporal_store(r, out + e);
}

extern "C" void kernel_launch(void* const* d_in, const int* in_sizes, int n_in,
                              void* d_out, int out_size, void* d_ws, size_t ws_size,
                              hipStream_t stream) {
  const float* x        = (const float*)d_in[0];
  const float* edge_attr= (const float*)d_in[1];
  const float* W        = (const float*)d_in[2];
  const float* W_edge   = (const float*)d_in[3];
  const float* att_src  = (const float*)d_in[4];
  const float* att_dst  = (const float*)d_in[5];
  const float* att_edge = (const float*)d_in[6];
  const float* bias     = (const float*)d_in[7];
  const float* lin_w    = (const float*)d_in[8];
  const float* lin_b    = (const float*)d_in[9];
  const int*   ei       = (const int*)d_in[10];
  float* out = (float*)d_out;

  // workspace layout (8-B alignment preserved: every region size mult of 8 B)
  char* base = (char*)d_ws;
  __hip_bfloat16* hbf = (__hip_bfloat16*)base;                      // 12.8 MB
  ull* sstream = (ull*)(base + (size_t)N_NODES * HDIM * 2);         // 8*210000*8 = 13.44 MB
  unsigned* bpack = (unsigned*)(sstream + (size_t)NSLICE * SLICE_CAP); // N*CAP*4 = 25.6 MB
  ull* packed = (ull*)(bpack + (size_t)N_NODES * CAP);              // N*8 = 0.8 MB (zeroed)
  unsigned* gcount = (unsigned*)(packed + N_NODES);                 // 8 u32 (zeroed)
  float* a_src  = (float*)(gcount + NSLICE);                        // N
  float* a_dst  = a_src + N_NODES;                                  // N
  float* s_node = a_dst + N_NODES;                                  // N
  float* w_e    = s_node + N_NODES;                                 // 16
  // total ~ 53.9 MB

  hipMemsetAsync(packed, 0, sizeof(ull) * N_NODES + sizeof(unsigned) * NSLICE, stream);

  int nb_node   = (N_NODES + 3) / 4;
  int nb_edge_t = N_EDGES / 256;   // 6250, exact

  k_node_h  <<<nb_node, 256, 0, stream>>>(x, W, att_src, att_dst, hbf, a_src, a_dst);
  k_we      <<<1, 64, 0, stream>>>(W_edge, att_edge, w_e);
  k_edge_pre<<<nb_edge_t, 256, 0, stream>>>(edge_attr, ei, w_e, a_src, a_dst,
                                            sstream, gcount);
  k_part2   <<<PART_BLOCKS, 256, 0, stream>>>(sstream, gcount, packed, bpack);
  k_gather  <<<nb_node, 256, 0, stream>>>(packed, bpack, hbf, a_src, a_dst,
                                          bias, lin_w, s_node);
  k_out     <<<nb_edge_t, 256, 0, stream>>>(ei, s_node, lin_b, out);
}

// Round 12
// 385.734 us; speedup vs baseline: 1.1040x; 1.0885x over previous
//
#include <hip/hip_runtime.h>
#include <hip/hip_bf16.h>
#include <hip/hip_fp16.h>
#include <math.h>

#define N_NODES 100000
#define N_EDGES 1600000
#define F_IN 16
#define HDIM 64
#define E_DIM 9
#define NEG 0.2f

#define CAP 64                            // bucket capacity/node (Poisson(16), 12-sigma)
#define NSLICE 8
#define SLICE_W 12500                     // dst-slice width (100000/8)
#define SLICE_CAP 210000                  // per-slice stream capacity (binomial +24 sigma)
#define PART_BLOCKS 1024                  // 8 slices x 128 blocks
#define FIXSCALE 16777216.0f              // 2^24 fixed-point for sum_ae
#define GPAD 64                           // gcount padding: 1 counter per 256 B line

typedef unsigned long long ull;
typedef long long ll;

// ---- K1: h = x@W (wave per node) -> bf16; a_src/a_dst computed in fp32 ----
__global__ __launch_bounds__(256) void k_node_h(
    const float* __restrict__ x, const float* __restrict__ W,
    const float* __restrict__ att_src, const float* __restrict__ att_dst,
    __hip_bfloat16* __restrict__ hbf, float* __restrict__ a_src,
    float* __restrict__ a_dst) {
  __shared__ float sW[F_IN * HDIM];
  int t = threadIdx.x;
  for (int i = t; i < F_IN * HDIM; i += 256) sW[i] = W[i];
  __syncthreads();
  int lane = t & 63;
  int node = blockIdx.x * 4 + (t >> 6);
  if (node >= N_NODES) return;
  const float* xr = x + node * F_IN;
  float acc = 0.f;
#pragma unroll
  for (int k = 0; k < F_IN; ++k) acc += xr[k] * sW[k * HDIM + lane];
  hbf[(size_t)node * HDIM + lane] = __float2bfloat16(acc);
  float v1 = acc * att_src[lane];
  float v2 = acc * att_dst[lane];
#pragma unroll
  for (int off = 32; off > 0; off >>= 1) {
    v1 += __shfl_down(v1, off);
    v2 += __shfl_down(v2, off);
  }
  if (lane == 0) { a_src[node] = v1; a_dst[node] = v2; }
}

// ---- tiny: w_e[d] = sum_h W_edge[d,h]*att_edge[h] ----
__global__ void k_we(const float* __restrict__ W_edge,
                     const float* __restrict__ att_edge, float* __restrict__ w_e) {
  int d = threadIdx.x;
  if (d < E_DIM) {
    float s = 0.f;
    for (int hh = 0; hh < HDIM; ++hh) s += W_edge[d * HDIM + hh] * att_edge[hh];
    w_e[d] = s;
  }
}

// ---- K2: per-edge math + 8-way dst-slice partition, ballot compaction.
// Reservation counters PADDED one per 256-B line: the R8-R10 ~120 us floor
// was 50K reservation atomics all hitting ONE line -> serialized at a single
// memory-side atomic unit. Padding -> 8-way parallel service.
// Entry = {dst_local:14 | fp16(a_e):16 | pk:32}. N_EDGES = 6250*256 exact. ----
__global__ __launch_bounds__(256) void k_edge_pre(
    const float* __restrict__ ea, const int* __restrict__ ei,
    const float* __restrict__ w_e, const float* __restrict__ a_src,
    const float* __restrict__ a_dst, ull* __restrict__ sstream,
    unsigned* __restrict__ gcount) {
  __shared__ float sea[256 * E_DIM];     // 9216 B staged edge_attr tile
  __shared__ float swe[E_DIM];
  __shared__ unsigned wcnt[4][NSLICE];   // per-wave per-slice counts
  __shared__ unsigned woff[4][NSLICE];   // per-wave exclusive prefix (block-local)
  __shared__ unsigned gbase[NSLICE];     // global reservation base
  int t = threadIdx.x;
  int wave = t >> 6, lane = t & 63;
  if (t < E_DIM) swe[t] = w_e[t];
  // coalesced stage: block's 256x9 floats, each byte read exactly once
  size_t tile = (size_t)blockIdx.x * (256 * E_DIM);
#pragma unroll
  for (int i = 0; i < E_DIM; ++i)
    sea[i * 256 + t] = __builtin_nontemporal_load(ea + tile + i * 256 + t);
  int e = blockIdx.x * 256 + t;
  int s = __builtin_nontemporal_load(ei + e);
  int d = __builtin_nontemporal_load(ei + N_EDGES + e);
  __syncthreads();
  float a_e = 0.f;
#pragma unroll
  for (int k = 0; k < E_DIM; ++k) a_e += sea[t * E_DIM + k] * swe[k];
  float al = a_src[s] + a_dst[d] + a_e;
  al = al >= 0.f ? al : NEG * al;
  float ee = expf(al);  // shift-invariant softmax: max-subtract skipped
  // round-to-nearest-even bf16; ee>0 so sign bit free -> 15 bits
  unsigned b = __float_as_uint(ee);
  b += 0x7fffu + ((b >> 16) & 1u);
  unsigned pk = ((unsigned)s << 15) | ((b >> 16) & 0x7fffu);
  unsigned slice = (unsigned)d / SLICE_W;
  unsigned dloc = (unsigned)d - slice * SLICE_W;
  unsigned aeh = (unsigned)__half_as_ushort(__float2half(a_e));
  ull entry = ((ull)dloc << 48) | ((ull)aeh << 32) | (ull)pk;
  // wave-level ranking via ballot (all lanes execute all 8 ballots)
  ull lt = (lane == 63) ? 0x7FFFFFFFFFFFFFFFull : ((1ull << lane) - 1ull);
  unsigned myrank = 0;
#pragma unroll
  for (int si = 0; si < NSLICE; ++si) {
    ull m = __ballot(slice == (unsigned)si);
    if (slice == (unsigned)si) myrank = (unsigned)__popcll(m & lt);
    if (lane == 0) wcnt[wave][si] = (unsigned)__popcll(m);
  }
  __syncthreads();
  if (t < NSLICE) {  // thread t handles slice t: per-wave prefix + reservation
    unsigned a = 0;
#pragma unroll
    for (int w = 0; w < 4; ++w) { woff[w][t] = a; a += wcnt[w][t]; }
    gbase[t] = atomicAdd(gcount + t * GPAD, a);   // padded: one line per counter
  }
  __syncthreads();
  unsigned off = gbase[slice] + woff[wave][slice] + myrank;
  if (off < SLICE_CAP)
    __builtin_nontemporal_store(entry, sstream + (size_t)slice * SLICE_CAP + off);
}

// ---- K3: distribute within slice. Each slice's entries are contiguous;
// every byte read once, coalesced. One fused 64-bit atomic per edge:
// count++ (low 20b, old value = bucket pos) + sum_ae in 2^-24 fixpt (high 44b).
// blockIdx%8 round-robin -> slice buckets (3.2 MB) stay in one XCD's L2. ----
__global__ __launch_bounds__(256) void k_part2(
    const ull* __restrict__ sstream, const unsigned* __restrict__ gcount,
    ull* __restrict__ packed, unsigned* __restrict__ bpack) {
  int t = threadIdx.x;
  int slice = blockIdx.x & (NSLICE - 1);
  int j = blockIdx.x >> 3;
  unsigned n = gcount[slice * GPAD];
  const ull* sp = sstream + (size_t)slice * SLICE_CAP;
  int lo = slice * SLICE_W;
  const unsigned stride = (PART_BLOCKS / NSLICE) * 256;
  for (unsigned i = (unsigned)j * 256 + t; i < n; i += stride) {
    ull entry = sp[i];
    int d = lo + (int)(unsigned)(entry >> 48);
    float ae = __half2float(__ushort_as_half((unsigned short)((entry >> 32) & 0xFFFFu)));
    unsigned pk = (unsigned)(entry & 0xFFFFFFFFu);
    ll q = (ll)lrintf(ae * FIXSCALE);
    ull old = atomicAdd(packed + d, ((ull)q << 20) | 1ull);
    unsigned pos = (unsigned)(old & 0xFFFFFu);
    if (pos < CAP) bpack[(size_t)d * CAP + pos] = pk;
  }
}

// ---- K4: gather: decode packed (deg+sum_ae), denom + weighted bf16-h
// aggregate from fixed-stride bucket (aligned uint4 loads, 8-way unroll),
// self-loop, relu/bias/lin_w dot (wave per node). ----
__global__ __launch_bounds__(256) void k_gather(
    const ull* __restrict__ packed, const unsigned* __restrict__ bpack,
    const __hip_bfloat16* __restrict__ hbf, const float* __restrict__ a_src,
    const float* __restrict__ a_dst, const float* __restrict__ bias,
    const float* __restrict__ lin_w, float* __restrict__ s_node) {
  int t = threadIdx.x;
  int lane = t & 63;
  int node = blockIdx.x * 4 + (t >> 6);
  if (node >= N_NODES) return;
  ull p = packed[node];
  unsigned deg = (unsigned)(p & 0xFFFFFu);
  float sumae = (float)((double)((ll)p >> 20) * (1.0 / (double)FIXSCALE));
  const unsigned* row = bpack + (size_t)node * CAP;
  float acc = 0.f, denom = 0.f;
  unsigned k = 0;
  for (; k + 8 <= deg; k += 8) {
    uint4 pa = *(const uint4*)(row + k);
    uint4 pb = *(const uint4*)(row + k + 4);
    float e0 = __uint_as_float((pa.x & 0x7fffu) << 16);
    float e1 = __uint_as_float((pa.y & 0x7fffu) << 16);
    float e2 = __uint_as_float((pa.z & 0x7fffu) << 16);
    float e3 = __uint_as_float((pa.w & 0x7fffu) << 16);
    float e4 = __uint_as_float((pb.x & 0x7fffu) << 16);
    float e5 = __uint_as_float((pb.y & 0x7fffu) << 16);
    float e6 = __uint_as_float((pb.z & 0x7fffu) << 16);
    float e7 = __uint_as_float((pb.w & 0x7fffu) << 16);
    float h0 = __bfloat162float(hbf[(size_t)(pa.x >> 15) * HDIM + lane]);
    float h1 = __bfloat162float(hbf[(size_t)(pa.y >> 15) * HDIM + lane]);
    float h2 = __bfloat162float(hbf[(size_t)(pa.z >> 15) * HDIM + lane]);
    float h3 = __bfloat162float(hbf[(size_t)(pa.w >> 15) * HDIM + lane]);
    float h4 = __bfloat162float(hbf[(size_t)(pb.x >> 15) * HDIM + lane]);
    float h5 = __bfloat162float(hbf[(size_t)(pb.y >> 15) * HDIM + lane]);
    float h6 = __bfloat162float(hbf[(size_t)(pb.z >> 15) * HDIM + lane]);
    float h7 = __bfloat162float(hbf[(size_t)(pb.w >> 15) * HDIM + lane]);
    denom += ((e0 + e1) + (e2 + e3)) + ((e4 + e5) + (e6 + e7));
    acc += (e0 * h0 + e1 * h1 + e2 * h2 + e3 * h3)
         + (e4 * h4 + e5 * h5 + e6 * h6 + e7 * h7);
  }
  for (; k + 4 <= deg; k += 4) {
    uint4 p4 = *(const uint4*)(row + k);
    float e0 = __uint_as_float((p4.x & 0x7fffu) << 16);
    float e1 = __uint_as_float((p4.y & 0x7fffu) << 16);
    float e2 = __uint_as_float((p4.z & 0x7fffu) << 16);
    float e3 = __uint_as_float((p4.w & 0x7fffu) << 16);
    float h0 = __bfloat162float(hbf[(size_t)(p4.x >> 15) * HDIM + lane]);
    float h1 = __bfloat162float(hbf[(size_t)(p4.y >> 15) * HDIM + lane]);
    float h2 = __bfloat162float(hbf[(size_t)(p4.z >> 15) * HDIM + lane]);
    float h3 = __bfloat162float(hbf[(size_t)(p4.w >> 15) * HDIM + lane]);
    denom += (e0 + e1) + (e2 + e3);
    acc += e0 * h0 + e1 * h1 + e2 * h2 + e3 * h3;
  }
  for (; k < deg; ++k) {
    unsigned pe = row[k];
    float ee = __uint_as_float((pe & 0x7fffu) << 16);
    denom += ee;
    acc += ee * __bfloat162float(hbf[(size_t)(pe >> 15) * HDIM + lane]);
  }
  // self-loop (fill_value='mean'): logit uses mean of incident a_e
  float cnt = (float)deg;
  float all = a_src[node] + a_dst[node] + sumae / fmaxf(cnt, 1.f);
  all = all >= 0.f ? all : NEG * all;
  float eel = expf(all);
  denom += eel;
  acc += eel * __bfloat162float(hbf[(size_t)node * HDIM + lane]);
  float o = fmaxf(acc / (denom + 1e-16f) + bias[lane], 0.f) * lin_w[lane];
#pragma unroll
  for (int off = 32; off > 0; off >>= 1) o += __shfl_down(o, off);
  if (lane == 0) s_node[node] = o;
}

// ---- K5: out[e] = sigmoid(0.5*(s[src]+s[dst]) + lin_b) ----
__global__ __launch_bounds__(256) void k_out(
    const int* __restrict__ ei, const float* __restrict__ s_node,
    const float* __restrict__ lin_b, float* __restrict__ out) {
  int e = blockIdx.x * 256 + threadIdx.x;
  if (e >= N_EDGES) return;
  int s = __builtin_nontemporal_load(ei + e);
  int d = __builtin_nontemporal_load(ei + N_EDGES + e);
  float z = 0.5f * (s_node[s] + s_node[d]) + lin_b[0];
  float r = 1.f / (1.f + expf(-z));
  __builtin_nontemporal_store(r, out + e);
}

extern "C" void kernel_launch(void* const* d_in, const int* in_sizes, int n_in,
                              void* d_out, int out_size, void* d_ws, size_t ws_size,
                              hipStream_t stream) {
  const float* x        = (const float*)d_in[0];
  const float* edge_attr= (const float*)d_in[1];
  const float* W        = (const float*)d_in[2];
  const float* W_edge   = (const float*)d_in[3];
  const float* att_src  = (const float*)d_in[4];
  const float* att_dst  = (const float*)d_in[5];
  const float* att_edge = (const float*)d_in[6];
  const float* bias     = (const float*)d_in[7];
  const float* lin_w    = (const float*)d_in[8];
  const float* lin_b    = (const float*)d_in[9];
  const int*   ei       = (const int*)d_in[10];
  float* out = (float*)d_out;

  // workspace layout (8-B alignment preserved: every region size mult of 8 B)
  char* base = (char*)d_ws;
  __hip_bfloat16* hbf = (__hip_bfloat16*)base;                      // 12.8 MB
  ull* sstream = (ull*)(base + (size_t)N_NODES * HDIM * 2);         // 8*210000*8 = 13.44 MB
  unsigned* bpack = (unsigned*)(sstream + (size_t)NSLICE * SLICE_CAP); // N*CAP*4 = 25.6 MB
  ull* packed = (ull*)(bpack + (size_t)N_NODES * CAP);              // N*8 = 0.8 MB (zeroed)
  unsigned* gcount = (unsigned*)(packed + N_NODES);                 // 8*64 u32 (zeroed)
  float* a_src  = (float*)(gcount + NSLICE * GPAD);                 // N
  float* a_dst  = a_src + N_NODES;                                  // N
  float* s_node = a_dst + N_NODES;                                  // N
  float* w_e    = s_node + N_NODES;                                 // 16
  // total ~ 53.9 MB

  hipMemsetAsync(packed, 0,
                 sizeof(ull) * N_NODES + sizeof(unsigned) * NSLICE * GPAD, stream);

  int nb_node   = (N_NODES + 3) / 4;
  int nb_edge_t = N_EDGES / 256;   // 6250, exact

  k_node_h  <<<nb_node, 256, 0, stream>>>(x, W, att_src, att_dst, hbf, a_src, a_dst);
  k_we      <<<1, 64, 0, stream>>>(W_edge, att_edge, w_e);
  k_edge_pre<<<nb_edge_t, 256, 0, stream>>>(edge_attr, ei, w_e, a_src, a_dst,
                                            sstream, gcount);
  k_part2   <<<PART_BLOCKS, 256, 0, stream>>>(sstream, gcount, packed, bpack);
  k_gather  <<<nb_node, 256, 0, stream>>>(packed, bpack, hbf, a_src, a_dst,
                                          bias, lin_w, s_node);
  k_out     <<<nb_edge_t, 256, 0, stream>>>(ei, s_node, lin_b, out);
}

// Round 13
// 362.956 us; speedup vs baseline: 1.1733x; 1.0628x over previous
//
#include <hip/hip_runtime.h>
#include <hip/hip_bf16.h>
#include <hip/hip_fp16.h>
#include <math.h>

#define N_NODES 100000
#define N_EDGES 1600000
#define F_IN 16
#define HDIM 64
#define E_DIM 9
#define NEG 0.2f

#define CAP 64                            // bucket capacity/node (Poisson(16), 12-sigma)
#define NSLICE 8
#define SLICE_W 12500                     // dst-slice width (100000/8)
#define SLICE_CAP 210000                  // per-slice stream capacity
#define PART_BLOCKS 1024                  // 8 slices x 128 blocks
#define FIXSCALE 16777216.0f              // 2^24 fixed-point for sum_ae
#define GPAD 64                           // gcount padding: 1 counter per 256 B line

typedef unsigned long long ull;
typedef long long ll;

__device__ __forceinline__ void bf2(unsigned u, float& lo, float& hi) {
  lo = __uint_as_float(u << 16);
  hi = __uint_as_float(u & 0xFFFF0000u);
}

// ---- K1: a_src/a_dst = (x@W)@att (wave per node); store x as bf16 row (32 B) ----
__global__ __launch_bounds__(256) void k_node_h(
    const float* __restrict__ x, const float* __restrict__ W,
    const float* __restrict__ att_src, const float* __restrict__ att_dst,
    __hip_bfloat16* __restrict__ xbf, float* __restrict__ a_src,
    float* __restrict__ a_dst) {
  __shared__ float sW[F_IN * HDIM];
  int t = threadIdx.x;
  for (int i = t; i < F_IN * HDIM; i += 256) sW[i] = W[i];
  __syncthreads();
  int lane = t & 63;
  int node = blockIdx.x * 4 + (t >> 6);
  if (node >= N_NODES) return;
  const float* xr = x + node * F_IN;
  float acc = 0.f;
#pragma unroll
  for (int k = 0; k < F_IN; ++k) acc += xr[k] * sW[k * HDIM + lane];
  if (lane < F_IN) xbf[(size_t)node * F_IN + lane] = __float2bfloat16(xr[lane]);
  float v1 = acc * att_src[lane];
  float v2 = acc * att_dst[lane];
#pragma unroll
  for (int off = 32; off > 0; off >>= 1) {
    v1 += __shfl_down(v1, off);
    v2 += __shfl_down(v2, off);
  }
  if (lane == 0) { a_src[node] = v1; a_dst[node] = v2; }
}

// ---- tiny: w_e[d] = sum_h W_edge[d,h]*att_edge[h] ----
__global__ void k_we(const float* __restrict__ W_edge,
                     const float* __restrict__ att_edge, float* __restrict__ w_e) {
  int d = threadIdx.x;
  if (d < E_DIM) {
    float s = 0.f;
    for (int hh = 0; hh < HDIM; ++hh) s += W_edge[d * HDIM + hh] * att_edge[hh];
    w_e[d] = s;
  }
}

// ---- K2: a_e dot + 8-way dst-slice partition (ballot compaction). NO random
// gathers, no exp — pure stream. Entry = {dloc:16 | fp16(a_e):16 | src:32}.
// gcount padded (R11: same-line atomics serialize ~2.5ns each). ----
__global__ __launch_bounds__(256) void k_edge_pre(
    const float* __restrict__ ea, const int* __restrict__ ei,
    const float* __restrict__ w_e, ull* __restrict__ sstream,
    unsigned* __restrict__ gcount) {
  __shared__ float sea[256 * E_DIM];
  __shared__ float swe[E_DIM];
  __shared__ unsigned wcnt[4][NSLICE];
  __shared__ unsigned woff[4][NSLICE];
  __shared__ unsigned gbase[NSLICE];
  int t = threadIdx.x;
  int wave = t >> 6, lane = t & 63;
  if (t < E_DIM) swe[t] = w_e[t];
  size_t tile = (size_t)blockIdx.x * (256 * E_DIM);
#pragma unroll
  for (int i = 0; i < E_DIM; ++i)
    sea[i * 256 + t] = __builtin_nontemporal_load(ea + tile + i * 256 + t);
  int e = blockIdx.x * 256 + t;
  int s = __builtin_nontemporal_load(ei + e);
  int d = __builtin_nontemporal_load(ei + N_EDGES + e);
  __syncthreads();
  float a_e = 0.f;
#pragma unroll
  for (int k = 0; k < E_DIM; ++k) a_e += sea[t * E_DIM + k] * swe[k];
  unsigned slice = (unsigned)d / SLICE_W;
  unsigned dloc = (unsigned)d - slice * SLICE_W;
  unsigned aeh = (unsigned)__half_as_ushort(__float2half(a_e));
  ull entry = ((ull)dloc << 48) | ((ull)aeh << 32) | (ull)(unsigned)s;
  // wave-level ranking via ballot
  ull lt = (lane == 63) ? 0x7FFFFFFFFFFFFFFFull : ((1ull << lane) - 1ull);
  unsigned myrank = 0;
#pragma unroll
  for (int si = 0; si < NSLICE; ++si) {
    ull m = __ballot(slice == (unsigned)si);
    if (slice == (unsigned)si) myrank = (unsigned)__popcll(m & lt);
    if (lane == 0) wcnt[wave][si] = (unsigned)__popcll(m);
  }
  __syncthreads();
  if (t < NSLICE) {
    unsigned a = 0;
#pragma unroll
    for (int w = 0; w < 4; ++w) { woff[w][t] = a; a += wcnt[w][t]; }
    gbase[t] = atomicAdd(gcount + t * GPAD, a);
  }
  __syncthreads();
  unsigned off = gbase[slice] + woff[wave][slice] + myrank;
  if (off < SLICE_CAP)
    __builtin_nontemporal_store(entry, sstream + (size_t)slice * SLICE_CAP + off);
}

// ---- K3: distribute within slice + FULL logit math (moved here: the a_src
// gather and exp hide under the atomic latency; a_dst is slice-local 50 KB).
// One fused 64-bit atomic per edge: count++ (low 20b, old = bucket pos) +
// sum_ae in 2^-24 fixpt (high 44b). blockIdx%8 -> XCD-resident bucket slice. ----
__global__ __launch_bounds__(256) void k_part2(
    const ull* __restrict__ sstream, const unsigned* __restrict__ gcount,
    const float* __restrict__ a_src, const float* __restrict__ a_dst,
    ull* __restrict__ packed, unsigned* __restrict__ bpack) {
  int t = threadIdx.x;
  int slice = blockIdx.x & (NSLICE - 1);
  int j = blockIdx.x >> 3;
  unsigned n = gcount[slice * GPAD];
  const ull* sp = sstream + (size_t)slice * SLICE_CAP;
  int lo = slice * SLICE_W;
  const unsigned stride = (PART_BLOCKS / NSLICE) * 256;
  for (unsigned i = (unsigned)j * 256 + t; i < n; i += stride) {
    ull entry = sp[i];
    unsigned src = (unsigned)(entry & 0xFFFFFFFFu);
    float ae = __half2float(__ushort_as_half((unsigned short)((entry >> 32) & 0xFFFFu)));
    int d = lo + (int)(unsigned)(entry >> 48);
    float al = a_src[src] + a_dst[d] + ae;
    al = al >= 0.f ? al : NEG * al;
    float ee = expf(al);  // shift-invariant softmax: max-subtract skipped
    unsigned b = __float_as_uint(ee);
    b += 0x7fffu + ((b >> 16) & 1u);
    unsigned pk = (src << 15) | ((b >> 16) & 0x7fffu);
    ll q = (ll)lrintf(ae * FIXSCALE);
    ull old = atomicAdd(packed + d, ((ull)q << 20) | 1ull);
    unsigned pos = (unsigned)(old & 0xFFFFFu);
    if (pos < CAP) bpack[(size_t)d * CAP + pos] = pk;
  }
}

// ---- K4: gather in x-space (rank-16): Sum ee*h[src] == (Sum ee*x[src])@W.
// 16 threads/node accumulate acc[16] from bf16 x rows (32 B/edge, 3.2 MB
// table -> L2-resident), shuffle-reduce, then 16x64 GEMV from LDS W with
// fused relu/bias/lin_w epilogue. ----
__global__ __launch_bounds__(256) void k_gather(
    const ull* __restrict__ packed, const unsigned* __restrict__ bpack,
    const __hip_bfloat16* __restrict__ xbf, const float* __restrict__ W,
    const float* __restrict__ a_src, const float* __restrict__ a_dst,
    const float* __restrict__ bias, const float* __restrict__ lin_w,
    float* __restrict__ s_node) {
  __shared__ float sW[F_IN * HDIM];
  int t = threadIdx.x;
  for (int i = t; i < F_IN * HDIM; i += 256) sW[i] = W[i];
  __syncthreads();
  int g = t >> 4, i = t & 15;
  int node = blockIdx.x * 16 + g;
  if (node >= N_NODES) return;
  ull p = packed[node];
  unsigned deg = (unsigned)(p & 0xFFFFFu);
  float sumae = (float)((double)((ll)p >> 20) * (1.0 / (double)FIXSCALE));
  unsigned degc = deg < CAP ? deg : CAP;
  const unsigned* row = bpack + (size_t)node * CAP;
  float acc[F_IN];
#pragma unroll
  for (int j = 0; j < F_IN; ++j) acc[j] = 0.f;
  float denom = 0.f;
  for (unsigned k = i; k < degc; k += 16) {
    unsigned pe = row[k];
    float ee = __uint_as_float((pe & 0x7fffu) << 16);
    unsigned src = pe >> 15;
    const uint4* xp = (const uint4*)(xbf + (size_t)src * F_IN);
    uint4 xa = xp[0], xb = xp[1];
    denom += ee;
    float f0, f1;
    bf2(xa.x, f0, f1); acc[0] += ee * f0; acc[1] += ee * f1;
    bf2(xa.y, f0, f1); acc[2] += ee * f0; acc[3] += ee * f1;
    bf2(xa.z, f0, f1); acc[4] += ee * f0; acc[5] += ee * f1;
    bf2(xa.w, f0, f1); acc[6] += ee * f0; acc[7] += ee * f1;
    bf2(xb.x, f0, f1); acc[8] += ee * f0; acc[9] += ee * f1;
    bf2(xb.y, f0, f1); acc[10] += ee * f0; acc[11] += ee * f1;
    bf2(xb.z, f0, f1); acc[12] += ee * f0; acc[13] += ee * f1;
    bf2(xb.w, f0, f1); acc[14] += ee * f0; acc[15] += ee * f1;
  }
  // reduce denom + acc[16] across the 16 lanes of this node-group
#pragma unroll
  for (int off = 8; off > 0; off >>= 1) {
    denom += __shfl_xor(denom, off, 16);
#pragma unroll
    for (int j = 0; j < F_IN; ++j) acc[j] += __shfl_xor(acc[j], off, 16);
  }
  // self-loop (fill_value='mean'): logit uses mean of incident a_e
  float cnt = (float)deg;
  float all = a_src[node] + a_dst[node] + sumae / fmaxf(cnt, 1.f);
  all = all >= 0.f ? all : NEG * all;
  float eel = expf(all);
  denom += eel;
  {
    const uint4* xp = (const uint4*)(xbf + (size_t)node * F_IN);
    uint4 xa = xp[0], xb = xp[1];
    float f0, f1;
    bf2(xa.x, f0, f1); acc[0] += eel * f0; acc[1] += eel * f1;
    bf2(xa.y, f0, f1); acc[2] += eel * f0; acc[3] += eel * f1;
    bf2(xa.z, f0, f1); acc[4] += eel * f0; acc[5] += eel * f1;
    bf2(xa.w, f0, f1); acc[6] += eel * f0; acc[7] += eel * f1;
    bf2(xb.x, f0, f1); acc[8] += eel * f0; acc[9] += eel * f1;
    bf2(xb.y, f0, f1); acc[10] += eel * f0; acc[11] += eel * f1;
    bf2(xb.z, f0, f1); acc[12] += eel * f0; acc[13] += eel * f1;
    bf2(xb.w, f0, f1); acc[14] += eel * f0; acc[15] += eel * f1;
  }
  float inv = 1.f / (denom + 1e-16f);
  // 16x64 GEMV + relu/bias/lin_w epilogue: lane i handles h = i+16*step
  float o = 0.f;
#pragma unroll
  for (int stp = 0; stp < 4; ++stp) {
    int h = i + stp * 16;
    float oh = 0.f;
#pragma unroll
    for (int j = 0; j < F_IN; ++j) oh += acc[j] * sW[j * HDIM + h];
    o += fmaxf(oh * inv + bias[h], 0.f) * lin_w[h];
  }
#pragma unroll
  for (int off = 8; off > 0; off >>= 1) o += __shfl_xor(o, off, 16);
  if (i == 0) s_node[node] = o;
}

// ---- K5: out[e] = sigmoid(0.5*(s[src]+s[dst]) + lin_b) ----
__global__ __launch_bounds__(256) void k_out(
    const int* __restrict__ ei, const float* __restrict__ s_node,
    const float* __restrict__ lin_b, float* __restrict__ out) {
  int e = blockIdx.x * 256 + threadIdx.x;
  if (e >= N_EDGES) return;
  int s = __builtin_nontemporal_load(ei + e);
  int d = __builtin_nontemporal_load(ei + N_EDGES + e);
  float z = 0.5f * (s_node[s] + s_node[d]) + lin_b[0];
  float r = 1.f / (1.f + expf(-z));
  __builtin_nontemporal_store(r, out + e);
}

extern "C" void kernel_launch(void* const* d_in, const int* in_sizes, int n_in,
                              void* d_out, int out_size, void* d_ws, size_t ws_size,
                              hipStream_t stream) {
  const float* x        = (const float*)d_in[0];
  const float* edge_attr= (const float*)d_in[1];
  const float* W        = (const float*)d_in[2];
  const float* W_edge   = (const float*)d_in[3];
  const float* att_src  = (const float*)d_in[4];
  const float* att_dst  = (const float*)d_in[5];
  const float* att_edge = (const float*)d_in[6];
  const float* bias     = (const float*)d_in[7];
  const float* lin_w    = (const float*)d_in[8];
  const float* lin_b    = (const float*)d_in[9];
  const int*   ei       = (const int*)d_in[10];
  float* out = (float*)d_out;

  // workspace layout (16-B alignment for xbf/sstream preserved)
  char* base = (char*)d_ws;
  __hip_bfloat16* xbf = (__hip_bfloat16*)base;                      // N*16*2 = 3.2 MB
  ull* sstream = (ull*)(base + (size_t)N_NODES * F_IN * 2);         // 8*210000*8 = 13.44 MB
  unsigned* bpack = (unsigned*)(sstream + (size_t)NSLICE * SLICE_CAP); // N*CAP*4 = 25.6 MB
  ull* packed = (ull*)(bpack + (size_t)N_NODES * CAP);              // N*8 = 0.8 MB (zeroed)
  unsigned* gcount = (unsigned*)(packed + N_NODES);                 // 8*64 u32 (zeroed)
  float* a_src  = (float*)(gcount + NSLICE * GPAD);                 // N
  float* a_dst  = a_src + N_NODES;                                  // N
  float* s_node = a_dst + N_NODES;                                  // N
  float* w_e    = s_node + N_NODES;                                 // 16
  // total ~ 44.3 MB

  hipMemsetAsync(packed, 0,
                 sizeof(ull) * N_NODES + sizeof(unsigned) * NSLICE * GPAD, stream);

  int nb_node   = (N_NODES + 3) / 4;
  int nb_edge_t = N_EDGES / 256;    // 6250, exact
  int nb_gather = (N_NODES + 15) / 16;

  k_node_h  <<<nb_node, 256, 0, stream>>>(x, W, att_src, att_dst, xbf, a_src, a_dst);
  k_we      <<<1, 64, 0, stream>>>(W_edge, att_edge, w_e);
  k_edge_pre<<<nb_edge_t, 256, 0, stream>>>(edge_attr, ei, w_e, sstream, gcount);
  k_part2   <<<PART_BLOCKS, 256, 0, stream>>>(sstream, gcount, a_src, a_dst,
                                              packed, bpack);
  k_gather  <<<nb_gather, 256, 0, stream>>>(packed, bpack, xbf, W, a_src, a_dst,
                                            bias, lin_w, s_node);
  k_out     <<<nb_edge_t, 256, 0, stream>>>(ei, s_node, lin_b, out);
}